// Round 9
// baseline (169.063 us; speedup 1.0000x reference)
//
#include <hip/hip_runtime.h>

// KPN per-pixel 5x5 predicted convolution, channels-last fp32.
// out[b,h,w,c] = sum_{i,j} feat[b,h+i-2,w+j-2,c] * kernel[b,h,w,i*5+j] + bias[c]
//
// Round 9 = best halves of R5 + R7, plus a register fence:
//  - Feat register-resident (R5: global clamped loads, deep MLP; LDS-feat R7
//    paid an LDS round-trip for every operand and plateaued the same).
//  - Weights via async global_load_lds DMA (R7/R8-proven: no VGPR payload,
//    no per-load waitcnt). OOB taps zeroed in LDS for edge blocks only ->
//    compute loop fully maskless (R5 spent 40 v_cndmask + per-col masks).
//  - sched_barrier(0) between feat rows 3|4 caps the live load window at
//    ~20 float4 -> fits __launch_bounds__(256,3) cap (~168 VGPR) WITHOUT
//    spill (R3/R4/R8: any cap below the full-unroll demand => scratch
//    traffic; R5's (256,2) avoided spill but left only 8 waves/CU).
//    (256,3) -> 12 waves/CU, 1.5x R5 residency, same MLP depth per half.
//  - XCD swizzle: 8 contiguous 256-tile H-bands, halo rows share an XCD L2.

#define BB 4
#define HH 256
#define WW 256
#define CC 32
#define KK 5
#define VH 4                   // output rows per thread/block
#define TW 32                  // tile width (pixels)
#define TPB 256
#define TROWS (VH + KK - 1)    // 8 feat rows
#define NW  (VH * TW * KK * KK)   // 3200 weight floats
#define NW4 (NW / 4)              // 800 float4
#define NQ  13                    // ceil(800/64) DMA wave-issues

typedef __attribute__((address_space(1))) const void gvoid_t;
typedef __attribute__((address_space(3))) void svoid_t;

__global__ __launch_bounds__(TPB, 3) void kpn_conv_kernel(
    const float* __restrict__ feat,
    const float* __restrict__ kern,
    const float* __restrict__ bias,
    float* __restrict__ out)
{
    __shared__ float4 skw4[NQ * 64];   // 832 f4 = 13.3 KB (800 + DMA tail pad)
    float* const skw = (float*)skw4;

    const int t    = threadIdx.x;
    const int lane = t & 63;
    const int wave = t >> 6;

    // XCD swizzle: blockIdx % 8 = XCD -> give each XCD a contiguous band.
    const int tile = ((blockIdx.x & 7) << 8) | (blockIdx.x >> 3);
    const int bw = tile & 7;             // W/TW = 8
    const int bh = (tile >> 3) & 63;     // H/VH = 64
    const int b  = tile >> 9;            // B = 4
    const int h0 = bh * VH;
    const int w0 = bw * TW;

    // ---- Async-stage weights: 13 wave-issues, zero VGPR payload. ----
    // Per output row oh: 32 px * 25 taps = 800 floats (200 f4) contiguous.
    {
        const float* kb = kern + (size_t)((b * HH + h0) * WW + w0) * (KK * KK);
        #pragma unroll
        for (int q = wave; q < NQ; q += TPB / 64) {
            int e   = (q << 6) + lane;
            int e4  = min(e, NW4 - 1);       // tail lanes duplicate into pad
            int oh  = e4 / 200;
            int off = (e4 - oh * 200) << 2;
            const float* gp = kb + (size_t)oh * (WW * KK * KK) + off;
            __builtin_amdgcn_global_load_lds((gvoid_t*)gp,
                                             (svoid_t*)(skw4 + (q << 6)),
                                             16, 0, 0);
        }
    }
    __syncthreads();   // drain DMA

    // ---- Edge blocks only: zero OOB taps in LDS (block-uniform branch). ----
    if (bh == 0 || bh == (HH / VH - 1) || bw == 0 || bw == (WW / TW - 1)) {
        for (int e = t; e < NW; e += TPB) {
            int oh  = e / (TW * KK * KK);        // /800
            int rem = e - oh * (TW * KK * KK);
            int wl  = rem / (KK * KK);           // /25
            int tap = rem - wl * (KK * KK);
            int i   = tap / KK;
            int j   = tap - i * KK;
            int hh  = h0 + oh + i - (KK / 2);
            int ww  = w0 + wl + j - (KK / 2);
            if (((unsigned)hh >= (unsigned)HH) || ((unsigned)ww >= (unsigned)WW))
                skw[e] = 0.0f;
        }
        __syncthreads();
    }

    // ---- Maskless compute: feat register-resident, clamped addresses. ----
    const int cg = (t & 7) << 2;   // channel group
    const int wL = t >> 3;         // 0..31
    const float* fb = feat + (((size_t)b) << 16) * CC;

    int wc[KK];
    #pragma unroll
    for (int j = 0; j < KK; ++j)
        wc[j] = min(max(w0 + wL + j - (KK / 2), 0), WW - 1);

    const float4 bz = *(const float4*)(bias + cg);
    float4 acc[VH];
    #pragma unroll
    for (int oh = 0; oh < VH; ++oh) acc[oh] = bz;

    #pragma unroll
    for (int r = 0; r < TROWS; ++r) {              // 8 rows, branch-free
        if (r == TROWS / 2) {
            // Register fence: cap live load window at ~20 f4 so the full
            // unroll fits the (256,3) VGPR budget without scratch spill.
            __builtin_amdgcn_sched_barrier(0);
        }
        const int hh = min(max(h0 + r - (KK / 2), 0), HH - 1);
        const float* rp = fb + (((size_t)hh) << 13);

        float4 f[KK];
        #pragma unroll
        for (int j = 0; j < KK; ++j)
            f[j] = *(const float4*)(rp + (wc[j] << 5) + cg);

        #pragma unroll
        for (int oh = 0; oh < VH; ++oh) {
            const int i = r - oh;                  // kernel row
            if (i >= 0 && i < KK) {                // compile-time after unroll
                const float* wp = skw + (oh * TW + wL) * (KK * KK) + i * KK;
                const float wg0 = wp[0], wg1 = wp[1], wg2 = wp[2],
                            wg3 = wp[3], wg4 = wp[4];
                acc[oh].x += f[0].x*wg0 + f[1].x*wg1 + f[2].x*wg2 + f[3].x*wg3 + f[4].x*wg4;
                acc[oh].y += f[0].y*wg0 + f[1].y*wg1 + f[2].y*wg2 + f[3].y*wg3 + f[4].y*wg4;
                acc[oh].z += f[0].z*wg0 + f[1].z*wg1 + f[2].z*wg2 + f[3].z*wg3 + f[4].z*wg4;
                acc[oh].w += f[0].w*wg0 + f[1].w*wg1 + f[2].w*wg2 + f[3].w*wg3 + f[4].w*wg4;
            }
        }
    }

    // ---- Coalesced stores: 4 rows x 1 KiB per wave. ----
    #pragma unroll
    for (int oh = 0; oh < VH; ++oh) {
        const size_t pix = (size_t)(b * HH + h0 + oh) * WW + (w0 + wL);
        *(float4*)(out + pix * CC + cg) = acc[oh];
    }
}

extern "C" void kernel_launch(void* const* d_in, const int* in_sizes, int n_in,
                              void* d_out, int out_size, void* d_ws, size_t ws_size,
                              hipStream_t stream) {
    const float* feat = (const float*)d_in[0];
    const float* kern = (const float*)d_in[1];
    const float* bias = (const float*)d_in[2];
    float* out = (float*)d_out;

    dim3 grid(BB * (HH / VH) * (WW / TW));  // 2048 blocks
    dim3 block(TPB);
    kpn_conv_kernel<<<grid, block, 0, stream>>>(feat, kern, bias, out);
}